// Round 1
// baseline (664.486 us; speedup 1.0000x reference)
//
#include <hip/hip_runtime.h>
#include <hip/hip_bf16.h>
#include <cstdint>
#include <cstddef>

// Problem constants
//   B = 16 batches, 4 scales, pooled spatial = 7x7 = 49
//   C per scale: 256, 512, 1024, 2048 ; H per scale: 56, 28, 14, 7 ; k = H/7
//
// Pipeline:
//   pool_kernel : act[B,C,H,H] -> pT[B,49,C]   (max-pool k x k, transposed store)
//   pair_kernel : per (scale,i,j) block:
//       S[e,f]   = sum_c pT[i,e,c]*pT[j,f,c]      (Gram, fp32)
//       heat     = softmax_f(S)                   (written to d_out)
//       out[e,c] = sum_f heat[e,f]*pT[j,f,c]      (written to d_out)

#define CC 64   // channel chunk staged in LDS per iteration

__global__ __launch_bounds__(256) void pool_kernel(const float* __restrict__ act,
                                                   float* __restrict__ pT,
                                                   int C, int H, int k, int G) {
    // grid: B * (C/G) blocks; each block stages G channel-planes (G*H*H == 3136)
    __shared__ float plane[3136];
    const int HW = H * H;
    const int nblk_c = C / G;
    const int i  = blockIdx.x / nblk_c;
    const int c0 = (blockIdx.x % nblk_c) * G;
    const float* src = act + ((size_t)i * C + c0) * HW;
    const int n = G * HW;
    for (int idx = threadIdx.x; idx < n; idx += 256)
        plane[idx] = src[idx];
    __syncthreads();
    const int nw = G * 49;
    for (int idx = threadIdx.x; idx < nw; idx += 256) {
        const int e = idx / G, g = idx % G;
        const int eh = e / 7, ew = e % 7;
        const float* pp = plane + g * HW + (eh * k) * H + ew * k;
        float m = -INFINITY;
        for (int dy = 0; dy < k; ++dy)
            for (int dx = 0; dx < k; ++dx)
                m = fmaxf(m, pp[dy * H + dx]);
        // transposed store: pT[i][e][c0+g]
        pT[((size_t)i * 49 + e) * C + c0 + g] = m;
    }
}

struct PairParams {
    const float* pT[4];
    float* out[4];
    float* heat[4];
    int C[4];
};

__global__ __launch_bounds__(256) void pair_kernel(PairParams P) {
    __shared__ float Ash[49 * 65];   // stride 65: bank-conflict-free column reads
    __shared__ float Bsh[49 * 65];
    __shared__ float Ssh[49 * 50];   // S / heat, stride 50

    const int s    = blockIdx.x & 3;        // interleave scales for load balance
    const int pair = blockIdx.x >> 2;       // 0..255
    const int i = pair >> 4, j = pair & 15;
    const int C = P.C[s];
    const float* pT = P.pT[s];
    const int tid = threadIdx.x;
    const int tx = tid & 15, ty = tid >> 4;

    const int e0 = ty, e1 = ty + 16, e2 = ty + 32;
    const int e3 = (ty + 48 < 49) ? (ty + 48) : 48;   // clamped (only ty==0 valid)
    const int f0 = tx, f1 = tx + 16, f2 = tx + 32;
    const int f3 = (tx + 48 < 49) ? (tx + 48) : 48;

    const float* pTi = pT + (size_t)i * 49 * C;
    const float* pTj = pT + (size_t)j * 49 * C;

    // ---------------- Gram: S[e,f] = sum_c pTi[e,c] * pTj[f,c] ----------------
    float acc[4][4];
    #pragma unroll
    for (int u = 0; u < 4; ++u)
        #pragma unroll
        for (int v = 0; v < 4; ++v) acc[u][v] = 0.f;

    for (int c0 = 0; c0 < C; c0 += CC) {
        for (int idx = tid; idx < 49 * CC; idx += 256) {
            const int e = idx >> 6, cc = idx & 63;
            Ash[e * 65 + cc] = pTi[e * C + c0 + cc];
            Bsh[e * 65 + cc] = pTj[e * C + c0 + cc];
        }
        __syncthreads();
        #pragma unroll 4
        for (int cc = 0; cc < CC; ++cc) {
            const float a0 = Ash[e0 * 65 + cc];
            const float a1 = Ash[e1 * 65 + cc];
            const float a2 = Ash[e2 * 65 + cc];
            const float a3 = Ash[e3 * 65 + cc];
            const float b0 = Bsh[f0 * 65 + cc];
            const float b1 = Bsh[f1 * 65 + cc];
            const float b2 = Bsh[f2 * 65 + cc];
            const float b3 = Bsh[f3 * 65 + cc];
            acc[0][0] += a0 * b0; acc[0][1] += a0 * b1; acc[0][2] += a0 * b2; acc[0][3] += a0 * b3;
            acc[1][0] += a1 * b0; acc[1][1] += a1 * b1; acc[1][2] += a1 * b2; acc[1][3] += a1 * b3;
            acc[2][0] += a2 * b0; acc[2][1] += a2 * b1; acc[2][2] += a2 * b2; acc[2][3] += a2 * b3;
            acc[3][0] += a3 * b0; acc[3][1] += a3 * b1; acc[3][2] += a3 * b2; acc[3][3] += a3 * b3;
        }
        __syncthreads();
    }

    // scatter S into LDS (only valid e,f)
    #pragma unroll
    for (int u = 0; u < 4; ++u) {
        const int e = ty + 16 * u;
        if (e < 49) {
            #pragma unroll
            for (int v = 0; v < 4; ++v) {
                const int f = tx + 16 * v;
                if (f < 49) Ssh[e * 50 + f] = acc[u][v];
            }
        }
    }
    __syncthreads();

    // ---------------- softmax over f (each of 49 rows) ----------------
    if (tid < 49) {
        float* row = Ssh + tid * 50;
        float m = row[0];
        #pragma unroll 7
        for (int f = 1; f < 49; ++f) m = fmaxf(m, row[f]);
        float sum = 0.f;
        #pragma unroll 7
        for (int f = 0; f < 49; ++f) {
            const float v = __expf(row[f] - m);
            row[f] = v;
            sum += v;
        }
        const float inv = 1.f / sum;
        #pragma unroll 7
        for (int f = 0; f < 49; ++f) row[f] *= inv;
    }
    __syncthreads();

    // write heat[i,j,e,f] coalesced
    {
        float* hout = P.heat[s] + (size_t)pair * 2401;
        for (int idx = tid; idx < 2401; idx += 256)
            hout[idx] = Ssh[(idx / 49) * 50 + (idx % 49)];
    }

    // ---------------- PV: out[e,c] = sum_f heat[e,f] * pTj[f,c] ----------------
    float* outp = P.out[s] + (size_t)pair * 49 * C;
    for (int c0 = 0; c0 < C; c0 += CC) {
        for (int idx = tid; idx < 49 * CC; idx += 256) {
            const int f = idx >> 6, cc = idx & 63;
            Ash[f * 65 + cc] = pTj[f * C + c0 + cc];
        }
        __syncthreads();
        float o[4][4];
        #pragma unroll
        for (int u = 0; u < 4; ++u)
            #pragma unroll
            for (int v = 0; v < 4; ++v) o[u][v] = 0.f;
        for (int f = 0; f < 49; ++f) {
            const float h0 = Ssh[e0 * 50 + f];
            const float h1 = Ssh[e1 * 50 + f];
            const float h2 = Ssh[e2 * 50 + f];
            const float h3 = Ssh[e3 * 50 + f];
            const float p0 = Ash[f * 65 + tx * 4 + 0];
            const float p1 = Ash[f * 65 + tx * 4 + 1];
            const float p2 = Ash[f * 65 + tx * 4 + 2];
            const float p3 = Ash[f * 65 + tx * 4 + 3];
            o[0][0] += h0 * p0; o[0][1] += h0 * p1; o[0][2] += h0 * p2; o[0][3] += h0 * p3;
            o[1][0] += h1 * p0; o[1][1] += h1 * p1; o[1][2] += h1 * p2; o[1][3] += h1 * p3;
            o[2][0] += h2 * p0; o[2][1] += h2 * p1; o[2][2] += h2 * p2; o[2][3] += h2 * p3;
            o[3][0] += h3 * p0; o[3][1] += h3 * p1; o[3][2] += h3 * p2; o[3][3] += h3 * p3;
        }
        #pragma unroll
        for (int u = 0; u < 4; ++u) {
            const int e = ty + 16 * u;
            if (e < 49) {
                float4 val = make_float4(o[u][0], o[u][1], o[u][2], o[u][3]);
                *reinterpret_cast<float4*>(&outp[(size_t)e * C + c0 + tx * 4]) = val;
            }
        }
        __syncthreads();
    }
}

extern "C" void kernel_launch(void* const* d_in, const int* in_sizes, int n_in,
                              void* d_out, int out_size, void* d_ws, size_t ws_size,
                              hipStream_t stream) {
    const float* act1 = (const float*)d_in[0];  // [16,256,56,56]
    const float* act2 = (const float*)d_in[1];  // [16,512,28,28]
    const float* act3 = (const float*)d_in[2];  // [16,1024,14,14]
    const float* act4 = (const float*)d_in[3];  // [16,2048,7,7]

    float* ws  = (float*)d_ws;
    float* pT1 = ws;                  // 16*49*256  = 200704 floats
    float* pT2 = pT1 + 200704;        // 16*49*512  = 401408
    float* pT3 = pT2 + 401408;        // 16*49*1024 = 802816
    float* pT4 = pT3 + 802816;        // 16*49*2048 = 1605632
    float* out = (float*)d_out;

    // pool: G chosen so G*H*H == 3136
    pool_kernel<<<16 * 256, 256, 0, stream>>>(act1, pT1, 256, 56, 8, 1);
    pool_kernel<<<16 * 128, 256, 0, stream>>>(act2, pT2, 512, 28, 4, 4);
    pool_kernel<<<16 * 64,  256, 0, stream>>>(act3, pT3, 1024, 14, 2, 16);
    pool_kernel<<<16 * 32,  256, 0, stream>>>(act4, pT4, 2048, 7, 1, 64);

    // output layout: out1..out4 then heat1..heat4, flat
    const size_t o1 = 0;
    const size_t o2 = o1 + (size_t)256 * 49 * 256;    // 3211264
    const size_t o3 = o2 + (size_t)256 * 49 * 512;    // 9633792
    const size_t o4 = o3 + (size_t)256 * 49 * 1024;   // 22478848
    const size_t h1 = o4 + (size_t)256 * 49 * 2048;   // 48168960
    const size_t h2 = h1 + (size_t)256 * 49 * 49;
    const size_t h3 = h2 + (size_t)256 * 49 * 49;
    const size_t h4 = h3 + (size_t)256 * 49 * 49;

    PairParams P;
    P.pT[0] = pT1; P.pT[1] = pT2; P.pT[2] = pT3; P.pT[3] = pT4;
    P.out[0] = out + o1; P.out[1] = out + o2; P.out[2] = out + o3; P.out[3] = out + o4;
    P.heat[0] = out + h1; P.heat[1] = out + h2; P.heat[2] = out + h3; P.heat[3] = out + h4;
    P.C[0] = 256; P.C[1] = 512; P.C[2] = 1024; P.C[3] = 2048;

    pair_kernel<<<4 * 256, 256, 0, stream>>>(P);
}

// Round 2
// 255.019 us; speedup vs baseline: 2.6056x; 2.6056x over previous
//
#include <hip/hip_runtime.h>
#include <hip/hip_bf16.h>
#include <cstdint>
#include <cstddef>

// B=16, 4 scales, pooled 7x7=49 -> padded to RPAD=56 rows per image.
// P[s] : [16*56][C] fp32, rows e in [49,56) zeroed.
// Gram : S[(i,e),(j,f)] = sum_c P[i,e,c]*P[j,f,c]  as 896x896 GEMM, split-K
// softmax over f (49) per (i,j,e), writes heat (i,j,e,f) output layout
// PV   : out[i,j,e,c] = sum_f heat*P[j,f,c]  as per-j GEMM, K=56

#define RPAD 56
#define MROWS 896        // 16*RPAD
#define TS 128
#define KC 32
#define LSTR 132         // LDS row stride (floats), mult-of-4 for b128 align
#define SPART 802816     // 896*896 floats per S partial

__global__ __launch_bounds__(256) void pool_kernel(const float* __restrict__ act,
                                                   float* __restrict__ P,
                                                   int C, int H, int k, int G) {
    __shared__ float plane[3136];
    const int HW = H * H;
    const int nblk_c = C / G;
    const int i  = blockIdx.x / nblk_c;
    const int c0 = (blockIdx.x % nblk_c) * G;
    const float* src = act + ((size_t)i * C + c0) * HW;
    for (int idx = threadIdx.x; idx < G * HW; idx += 256)
        plane[idx] = src[idx];
    __syncthreads();
    for (int idx = threadIdx.x; idx < G * 49; idx += 256) {
        const int e = idx / G, g = idx % G;
        const int eh = e / 7, ew = e % 7;
        const float* pp = plane + g * HW + (eh * k) * H + ew * k;
        float m = -INFINITY;
        for (int dy = 0; dy < k; ++dy)
            for (int dx = 0; dx < k; ++dx)
                m = fmaxf(m, pp[dy * H + dx]);
        P[((size_t)i * RPAD + e) * C + c0 + g] = m;
    }
    // zero the pad rows e=49..55 for this channel slice
    for (int idx = threadIdx.x; idx < 7 * G; idx += 256) {
        const int e = 49 + idx / G, g = idx % G;
        P[((size_t)i * RPAD + e) * C + c0 + g] = 0.f;
    }
}

__device__ __forceinline__ void fma44(float acc[4][4], const float4 a, const float4 b) {
    const float av[4] = {a.x, a.y, a.z, a.w};
    const float bv[4] = {b.x, b.y, b.z, b.w};
    #pragma unroll
    for (int u = 0; u < 4; ++u)
        #pragma unroll
        for (int v = 0; v < 4; ++v)
            acc[u][v] += av[u] * bv[v];
}

struct GramParams {
    const float* P[4];
    float* S[4];        // base of split-K partial buffers (parts consecutive)
    int C[4];
    int np[4];
    int cum[5];         // cumulative block counts (np[s]*49)
};

__global__ __launch_bounds__(256) void gram_kernel(GramParams g) {
    __shared__ float AT[KC][LSTR];
    __shared__ float BT[KC][LSTR];
    int b = blockIdx.x, s = 0;
    while (b >= g.cum[s + 1]) s++;
    const int rem = b - g.cum[s];
    const int p = rem / 49, t = rem % 49;
    const int bi = t / 7, bj = t % 7;
    const int C = g.C[s];
    const int Klen = C / g.np[s];          // 256 in full mode
    const int k0 = p * Klen;
    const float* __restrict__ X = g.P[s];
    float* __restrict__ S = g.S[s] + (size_t)p * SPART;

    const int tid = threadIdx.x;
    const int tx = tid & 15, ty = tid >> 4;

    float acc[2][2][4][4];
    #pragma unroll
    for (int a = 0; a < 2; ++a)
        #pragma unroll
        for (int c = 0; c < 2; ++c)
            #pragma unroll
            for (int u = 0; u < 4; ++u)
                #pragma unroll
                for (int v = 0; v < 4; ++v) acc[a][c][u][v] = 0.f;

    const float* Arow = X + (size_t)(bi * TS) * C;
    const float* Brow = X + (size_t)(bj * TS) * C;

    for (int kc = 0; kc < Klen; kc += KC) {
        #pragma unroll
        for (int q = 0; q < 4; ++q) {
            const int id = q * 256 + tid;        // 0..1023
            const int r  = id >> 3;              // 0..127
            const int kq = id & 7;               // float4 index along k
            const size_t go = (size_t)r * C + k0 + kc + kq * 4;
            const float4 va = *reinterpret_cast<const float4*>(&Arow[go]);
            AT[kq * 4 + 0][r] = va.x; AT[kq * 4 + 1][r] = va.y;
            AT[kq * 4 + 2][r] = va.z; AT[kq * 4 + 3][r] = va.w;
            const float4 vb = *reinterpret_cast<const float4*>(&Brow[go]);
            BT[kq * 4 + 0][r] = vb.x; BT[kq * 4 + 1][r] = vb.y;
            BT[kq * 4 + 2][r] = vb.z; BT[kq * 4 + 3][r] = vb.w;
        }
        __syncthreads();
        #pragma unroll 4
        for (int kk = 0; kk < KC; ++kk) {
            const float4 a0 = *reinterpret_cast<const float4*>(&AT[kk][ty * 4]);
            const float4 a1 = *reinterpret_cast<const float4*>(&AT[kk][64 + ty * 4]);
            const float4 b0 = *reinterpret_cast<const float4*>(&BT[kk][tx * 4]);
            const float4 b1 = *reinterpret_cast<const float4*>(&BT[kk][64 + tx * 4]);
            fma44(acc[0][0], a0, b0);
            fma44(acc[0][1], a0, b1);
            fma44(acc[1][0], a1, b0);
            fma44(acc[1][1], a1, b1);
        }
        __syncthreads();
    }

    #pragma unroll
    for (int a = 0; a < 2; ++a)
        #pragma unroll
        for (int u = 0; u < 4; ++u) {
            const int r = bi * TS + a * 64 + ty * 4 + u;
            #pragma unroll
            for (int c = 0; c < 2; ++c) {
                const int cc = bj * TS + c * 64 + tx * 4;
                float4 v = make_float4(acc[a][c][u][0], acc[a][c][u][1],
                                       acc[a][c][u][2], acc[a][c][u][3]);
                *reinterpret_cast<float4*>(&S[(size_t)r * MROWS + cc]) = v;
            }
        }
}

struct SoftParams {
    const float* S[4];
    float* heat[4];
    int np[4];
};

__global__ __launch_bounds__(256) void softmax_kernel(SoftParams sp) {
    const int grp = (blockIdx.x * 256 + threadIdx.x) >> 4;   // 0..50175
    const int l = threadIdx.x & 15;
    const int s = grp / 12544;
    const int rem = grp % 12544;
    const int i = rem / 784;
    const int j = (rem / 49) % 16;
    const int e = rem % 49;
    const float* __restrict__ Sb = sp.S[s];
    const int np = sp.np[s];
    const size_t rowoff = ((size_t)(i * RPAD + e)) * MROWS + j * RPAD;

    float v[4];
    #pragma unroll
    for (int t = 0; t < 4; ++t) {
        const int f = l + t * 16;
        float x = -INFINITY;
        if (f < 49) {
            x = 0.f;
            for (int p = 0; p < np; ++p) x += Sb[(size_t)p * SPART + rowoff + f];
        }
        v[t] = x;
    }
    float m = fmaxf(fmaxf(v[0], v[1]), fmaxf(v[2], v[3]));
    #pragma unroll
    for (int d = 1; d < 16; d <<= 1) m = fmaxf(m, __shfl_xor(m, d, 16));
    float ex[4], sum = 0.f;
    #pragma unroll
    for (int t = 0; t < 4; ++t) {
        const int f = l + t * 16;
        ex[t] = (f < 49) ? __expf(v[t] - m) : 0.f;
        sum += ex[t];
    }
    #pragma unroll
    for (int d = 1; d < 16; d <<= 1) sum += __shfl_xor(sum, d, 16);
    const float inv = 1.f / sum;
    float* hbase = sp.heat[s] + (((size_t)(i * 16 + j)) * 49 + e) * 49;
    #pragma unroll
    for (int t = 0; t < 4; ++t) {
        const int f = l + t * 16;
        if (f < 49) hbase[f] = ex[t] * inv;
    }
}

struct PvParams {
    const float* P[4];
    const float* heat[4];
    float* out[4];
    int C[4];
    int cum[5];
};

__global__ __launch_bounds__(256) void pv_kernel(PvParams pv) {
    __shared__ float AT[28][LSTR];   // heat^T chunk: AT[f][row]
    __shared__ float BT[28][LSTR];   // P rows chunk: BT[f][c]
    int b = blockIdx.x, s = 0;
    while (b >= pv.cum[s + 1]) s++;
    const int rem = b - pv.cum[s];
    const int C = pv.C[s];
    const int nct = C >> 7;
    const int j = rem / (7 * nct);
    const int rem2 = rem % (7 * nct);
    const int rt = rem2 / nct, ct = rem2 % nct;
    const int tid = threadIdx.x, tx = tid & 15, ty = tid >> 4;
    const float* __restrict__ hb = pv.heat[s];
    const float* __restrict__ Pj = pv.P[s] + (size_t)(j * RPAD) * C + ct * TS;

    float acc[2][2][4][4];
    #pragma unroll
    for (int a = 0; a < 2; ++a)
        #pragma unroll
        for (int c = 0; c < 2; ++c)
            #pragma unroll
            for (int u = 0; u < 4; ++u)
                #pragma unroll
                for (int v = 0; v < 4; ++v) acc[a][c][u][v] = 0.f;

    for (int f0 = 0; f0 < 56; f0 += 28) {
        // stage B: BT[ff][c] = Pj[(f0+ff)*C + c]
        for (int id = tid; id < 28 * 32; id += 256) {
            const int ff = id >> 5, cq = id & 31;
            const float4 vb = *reinterpret_cast<const float4*>(&Pj[(size_t)(f0 + ff) * C + cq * 4]);
            *reinterpret_cast<float4*>(&BT[ff][cq * 4]) = vb;
        }
        // stage A: AT[ff][r] = heat[i,j,e,f0+ff] (0 if e>=49 or f>=49)
        for (int id = tid; id < 28 * 128; id += 256) {
            const int r = id / 28, ff = id % 28;
            const int R = rt * TS + r;
            const int ii = R / RPAD, e = R % RPAD;
            const int f = f0 + ff;
            float v = 0.f;
            if (e < 49 && f < 49)
                v = hb[(((size_t)(ii * 16 + j)) * 49 + e) * 49 + f];
            AT[ff][r] = v;
        }
        __syncthreads();
        #pragma unroll 4
        for (int kk = 0; kk < 28; ++kk) {
            const float4 a0 = *reinterpret_cast<const float4*>(&AT[kk][ty * 4]);
            const float4 a1 = *reinterpret_cast<const float4*>(&AT[kk][64 + ty * 4]);
            const float4 b0 = *reinterpret_cast<const float4*>(&BT[kk][tx * 4]);
            const float4 b1 = *reinterpret_cast<const float4*>(&BT[kk][64 + tx * 4]);
            fma44(acc[0][0], a0, b0);
            fma44(acc[0][1], a0, b1);
            fma44(acc[1][0], a1, b0);
            fma44(acc[1][1], a1, b1);
        }
        __syncthreads();
    }

    #pragma unroll
    for (int a = 0; a < 2; ++a)
        #pragma unroll
        for (int u = 0; u < 4; ++u) {
            const int R = rt * TS + a * 64 + ty * 4 + u;
            const int ii = R / RPAD, e = R % RPAD;
            if (e < 49) {
                float* op = pv.out[s] + (((size_t)(ii * 16 + j)) * 49 + e) * C + ct * TS;
                #pragma unroll
                for (int c = 0; c < 2; ++c) {
                    float4 v = make_float4(acc[a][c][u][0], acc[a][c][u][1],
                                           acc[a][c][u][2], acc[a][c][u][3]);
                    *reinterpret_cast<float4*>(&op[c * 64 + tx * 4]) = v;
                }
            }
        }
}

extern "C" void kernel_launch(void* const* d_in, const int* in_sizes, int n_in,
                              void* d_out, int out_size, void* d_ws, size_t ws_size,
                              hipStream_t stream) {
    const float* act1 = (const float*)d_in[0];
    const float* act2 = (const float*)d_in[1];
    const float* act3 = (const float*)d_in[2];
    const float* act4 = (const float*)d_in[3];

    float* ws = (float*)d_ws;
    // padded P buffers
    float* P1 = ws;                         // 896*256
    float* P2 = P1 + (size_t)MROWS * 256;   // 896*512
    float* P3 = P2 + (size_t)MROWS * 512;
    float* P4 = P3 + (size_t)MROWS * 1024;
    float* Sbase = P4 + (size_t)MROWS * 2048;   // offset 3440640 floats

    const bool full = ws_size >= (size_t)(3440640 + 15 * SPART) * 4;
    int np[4];
    if (full) { np[0] = 1; np[1] = 2; np[2] = 4; np[3] = 8; }
    else      { np[0] = 1; np[1] = 1; np[2] = 1; np[3] = 1; }

    float* Sp[4];
    Sp[0] = Sbase;
    Sp[1] = Sp[0] + (size_t)np[0] * SPART;
    Sp[2] = Sp[1] + (size_t)np[1] * SPART;
    Sp[3] = Sp[2] + (size_t)np[2] * SPART;

    float* out = (float*)d_out;
    const size_t o1 = 0;
    const size_t o2 = o1 + (size_t)256 * 49 * 256;
    const size_t o3 = o2 + (size_t)256 * 49 * 512;
    const size_t o4 = o3 + (size_t)256 * 49 * 1024;
    const size_t h1 = o4 + (size_t)256 * 49 * 2048;
    const size_t h2 = h1 + (size_t)256 * 2401;
    const size_t h3 = h2 + (size_t)256 * 2401;
    const size_t h4 = h3 + (size_t)256 * 2401;

    pool_kernel<<<16 * 256, 256, 0, stream>>>(act1, P1, 256, 56, 8, 1);
    pool_kernel<<<16 * 128, 256, 0, stream>>>(act2, P2, 512, 28, 4, 4);
    pool_kernel<<<16 * 64,  256, 0, stream>>>(act3, P3, 1024, 14, 2, 16);
    pool_kernel<<<16 * 32,  256, 0, stream>>>(act4, P4, 2048, 7, 1, 64);

    GramParams g;
    g.P[0] = P1; g.P[1] = P2; g.P[2] = P3; g.P[3] = P4;
    g.S[0] = Sp[0]; g.S[1] = Sp[1]; g.S[2] = Sp[2]; g.S[3] = Sp[3];
    g.C[0] = 256; g.C[1] = 512; g.C[2] = 1024; g.C[3] = 2048;
    g.cum[0] = 0;
    for (int s = 0; s < 4; ++s) { g.np[s] = np[s]; g.cum[s + 1] = g.cum[s] + np[s] * 49; }
    gram_kernel<<<g.cum[4], 256, 0, stream>>>(g);

    SoftParams sp;
    for (int s = 0; s < 4; ++s) { sp.S[s] = Sp[s]; sp.np[s] = np[s]; }
    sp.heat[0] = out + h1; sp.heat[1] = out + h2; sp.heat[2] = out + h3; sp.heat[3] = out + h4;
    softmax_kernel<<<3136, 256, 0, stream>>>(sp);

    PvParams pv;
    pv.P[0] = P1; pv.P[1] = P2; pv.P[2] = P3; pv.P[3] = P4;
    pv.heat[0] = out + h1; pv.heat[1] = out + h2; pv.heat[2] = out + h3; pv.heat[3] = out + h4;
    pv.out[0] = out + o1; pv.out[1] = out + o2; pv.out[2] = out + o3; pv.out[3] = out + o4;
    pv.C[0] = 256; pv.C[1] = 512; pv.C[2] = 1024; pv.C[3] = 2048;
    pv.cum[0] = 0;
    for (int s = 0; s < 4; ++s) pv.cum[s + 1] = pv.cum[s] + 16 * 7 * (pv.C[s] >> 7);
    pv_kernel<<<pv.cum[4], 256, 0, stream>>>(pv);
}

// Round 4
// 164.686 us; speedup vs baseline: 4.0349x; 1.5485x over previous
//
#include <hip/hip_runtime.h>
#include <hip/hip_bf16.h>
#include <cstdint>
#include <cstddef>

// B=16 images, 4 scales, pooled 7x7=49 spatial, rows padded to 56 (MROWS=896).
//
// pool    : act -> Pk[s]  bf16 k-grouped [2C/8][896][8]  ([hi,lo] per channel)
//                  Pk2[s] same but [lo,hi] swapped        (cross-term operand)
//                  Vb[s]  bf16 k-grouped [16 j][8 kq][C][8]   (V^T, f padded to 64)
// gram    : S = P·P^T exact-split bf16 MFMA: A=[hi,lo]; B=Pk gives hi*hi+lo*lo,
//           B2=Pk2 gives hi*lo+lo*hi; sum == (hi+lo)*(hi+lo). fp32 acc, split-K.
// softmax : sums partials, softmax over f, writes heat (fp32 out) + Hb bf16
//                  Hb[s]  [16 j][8 kq][896][8]  (heat, f padded to 64)
// pv      : out[(i,e),c] = sum_f Hb*Vb  bf16 MFMA per (s,j,rowtile,coltile)

typedef __attribute__((ext_vector_type(8))) short s16x8;
typedef __attribute__((ext_vector_type(4))) float f32x4;

#define SPART 802816   // 896*896

__device__ __forceinline__ unsigned short f2bf(float x) {
    uint32_t u = __float_as_uint(x);
    uint32_t r = (u + 0x7fff + ((u >> 16) & 1)) >> 16;
    return (unsigned short)r;
}
__device__ __forceinline__ float bf2f(unsigned short b) {
    return __uint_as_float(((uint32_t)b) << 16);
}
__device__ __forceinline__ void gll16(const void* g, void* l) {
    __builtin_amdgcn_global_load_lds(
        (const __attribute__((address_space(1))) uint32_t*)g,
        (__attribute__((address_space(3))) uint32_t*)l, 16, 0, 0);
}

__global__ __launch_bounds__(256) void pool_kernel(const float* __restrict__ act,
                                                   unsigned short* __restrict__ Pk,
                                                   unsigned short* __restrict__ Pk2,
                                                   unsigned short* __restrict__ Vb,
                                                   int C, int H, int k, int G) {
    __shared__ float plane[3136];
    const int HW = H * H;
    const int nblk_c = C / G;
    const int i  = blockIdx.x / nblk_c;
    const int c0 = (blockIdx.x % nblk_c) * G;
    const float* src = act + ((size_t)i * C + c0) * HW;
    for (int idx = threadIdx.x; idx < G * HW; idx += 256)
        plane[idx] = src[idx];
    __syncthreads();
    for (int idx = threadIdx.x; idx < G * 49; idx += 256) {
        const int e = idx / G, g = idx % G;
        const int eh = e / 7, ew = e % 7;
        const float* pp = plane + g * HW + (eh * k) * H + ew * k;
        float m = -INFINITY;
        for (int dy = 0; dy < k; ++dy)
            for (int dx = 0; dx < k; ++dx)
                m = fmaxf(m, pp[dy * H + dx]);
        const int c = c0 + g;
        const unsigned short hb = f2bf(m);
        const unsigned short lb = f2bf(m - bf2f(hb));
        const size_t pk = (((size_t)(c >> 2) * 896) + (size_t)i * 56 + e) * 8 + ((c & 3) * 2);
        *reinterpret_cast<uint32_t*>(&Pk[pk])  = (uint32_t)hb | ((uint32_t)lb << 16);
        *reinterpret_cast<uint32_t*>(&Pk2[pk]) = (uint32_t)lb | ((uint32_t)hb << 16);
        const size_t vb = (((size_t)i * 8 + (e >> 3)) * C + c) * 8 + (e & 7);
        Vb[vb] = hb;
    }
    // Pk/Pk2 pad rows e=49..55 -> zero
    for (int idx = threadIdx.x; idx < 7 * G; idx += 256) {
        const int e = 49 + idx / G, g = idx % G, c = c0 + g;
        const size_t pk = (((size_t)(c >> 2) * 896) + (size_t)i * 56 + e) * 8 + ((c & 3) * 2);
        *reinterpret_cast<uint32_t*>(&Pk[pk])  = 0;
        *reinterpret_cast<uint32_t*>(&Pk2[pk]) = 0;
    }
    // Vb pad f=49..63 -> zero
    for (int idx = threadIdx.x; idx < 15 * G; idx += 256) {
        const int e = 49 + idx / G, g = idx % G, c = c0 + g;
        const size_t vb = (((size_t)i * 8 + (e >> 3)) * C + c) * 8 + (e & 7);
        Vb[vb] = 0;
    }
}

struct GramParams {
    const unsigned short* Pk[4];
    const unsigned short* Pk2[4];
    float* S[4];
    int Kblk[4];   // k' elements per block per pass (=2C/np)
    int cum[5];
};

__global__ __launch_bounds__(256) void gram_kernel(GramParams g) {
    __shared__ short lsA[4 * 128 * 8];
    __shared__ short lsB[4 * 128 * 8];
    __shared__ short lsB2[4 * 128 * 8];
    int b = blockIdx.x, s = 0;
    while (b >= g.cum[s + 1]) s++;
    const int rem = b - g.cum[s];
    const int p = rem / 49, t = rem % 49;
    const int bi = t / 7, bj = t % 7;
    const int Kb = g.Kblk[s];
    const int kg0 = p * (Kb >> 3);
    const unsigned short* __restrict__ Pk  = g.Pk[s];
    const unsigned short* __restrict__ Pk2 = g.Pk2[s];
    float* __restrict__ S = g.S[s] + (size_t)p * SPART;

    const int tid = threadIdx.x, lane = tid & 63, w = tid >> 6;
    const int wm = (w >> 1) * 64, wn = (w & 1) * 64;

    f32x4 acc[4][4];
    #pragma unroll
    for (int u = 0; u < 4; ++u)
        #pragma unroll
        for (int v = 0; v < 4; ++v)
            acc[u][v] = (f32x4){0.f, 0.f, 0.f, 0.f};

    const int half = lane >> 4, r16 = lane & 15;
    for (int it = 0; it < (Kb >> 5); ++it) {
        const int kq = kg0 + it * 4 + w;
        const char* ga  = (const char*)Pk  + ((size_t)kq * 896 + bi * 128) * 16 + lane * 16;
        const char* gb  = (const char*)Pk  + ((size_t)kq * 896 + bj * 128) * 16 + lane * 16;
        const char* gb2 = (const char*)Pk2 + ((size_t)kq * 896 + bj * 128) * 16 + lane * 16;
        gll16(ga,         (char*)lsA  + w * 2048);
        gll16(ga  + 1024, (char*)lsA  + w * 2048 + 1024);
        gll16(gb,         (char*)lsB  + w * 2048);
        gll16(gb  + 1024, (char*)lsB  + w * 2048 + 1024);
        gll16(gb2,        (char*)lsB2 + w * 2048);
        gll16(gb2 + 1024, (char*)lsB2 + w * 2048 + 1024);
        __syncthreads();
        s16x8 av[4], bv[4], cv[4];
        #pragma unroll
        for (int u = 0; u < 4; ++u) {
            av[u] = *reinterpret_cast<const s16x8*>(&lsA [((half * 128) + wm + 16 * u + r16) * 8]);
            bv[u] = *reinterpret_cast<const s16x8*>(&lsB [((half * 128) + wn + 16 * u + r16) * 8]);
            cv[u] = *reinterpret_cast<const s16x8*>(&lsB2[((half * 128) + wn + 16 * u + r16) * 8]);
        }
        #pragma unroll
        for (int u = 0; u < 4; ++u)
            #pragma unroll
            for (int v = 0; v < 4; ++v) {
                acc[u][v] = __builtin_amdgcn_mfma_f32_16x16x32_bf16(av[u], bv[v], acc[u][v], 0, 0, 0);
                acc[u][v] = __builtin_amdgcn_mfma_f32_16x16x32_bf16(av[u], cv[v], acc[u][v], 0, 0, 0);
            }
        __syncthreads();
    }

    const int rowb = bi * 128 + wm + (lane >> 4) * 4;
    const int colb = bj * 128 + wn + (lane & 15);
    #pragma unroll
    for (int u = 0; u < 4; ++u)
        #pragma unroll
        for (int v = 0; v < 4; ++v)
            #pragma unroll
            for (int rg = 0; rg < 4; ++rg)
                S[(size_t)(rowb + 16 * u + rg) * 896 + colb + 16 * v] = acc[u][v][rg];
}

struct SoftParams {
    const float* S[4];
    float* heat[4];
    unsigned short* Hb[4];
    int np[4];
};

__global__ __launch_bounds__(256) void softmax_kernel(SoftParams sp) {
    const int grp = (blockIdx.x * 256 + threadIdx.x) >> 4;
    const int l = threadIdx.x & 15;
    const int s = grp / 12544;
    const int rem = grp % 12544;
    const int i = rem / 784;
    const int j = (rem / 49) % 16;
    const int e = rem % 49;
    const float* __restrict__ Sb = sp.S[s];
    const int np = sp.np[s];
    const size_t rowoff = ((size_t)(i * 56 + e)) * 896 + j * 56;

    float v[4];
    #pragma unroll
    for (int t = 0; t < 4; ++t) {
        const int f = l + t * 16;
        float x = -INFINITY;
        if (f < 49) {
            x = 0.f;
            for (int p = 0; p < np; ++p) x += Sb[(size_t)p * SPART + rowoff + f];
        }
        v[t] = x;
    }
    float m = fmaxf(fmaxf(v[0], v[1]), fmaxf(v[2], v[3]));
    #pragma unroll
    for (int d = 1; d < 16; d <<= 1) m = fmaxf(m, __shfl_xor(m, d, 16));
    float ex[4], sum = 0.f;
    #pragma unroll
    for (int t = 0; t < 4; ++t) {
        const int f = l + t * 16;
        ex[t] = (f < 49) ? __expf(v[t] - m) : 0.f;
        sum += ex[t];
    }
    #pragma unroll
    for (int d = 1; d < 16; d <<= 1) sum += __shfl_xor(sum, d, 16);
    const float inv = 1.f / sum;

    float* hrow = sp.heat[s] + (((size_t)(i * 16 + j)) * 49 + e) * 49;
    unsigned short* __restrict__ Hb = sp.Hb[s];
    const size_t hbrow = (size_t)i * 56 + e;
    #pragma unroll
    for (int t = 0; t < 4; ++t) {
        const int f = l + t * 16;
        const float hv = (f < 49) ? ex[t] * inv : 0.f;
        if (f < 49) hrow[f] = hv;
        Hb[(((size_t)j * 8 + (f >> 3)) * 896 + hbrow) * 8 + (f & 7)] = f2bf(hv);
    }
}

struct PvParams {
    const unsigned short* Hb[4];
    const unsigned short* Vb[4];
    float* out[4];
    int C[4];
    int cum[5];
};

__global__ __launch_bounds__(256) void pv_kernel(PvParams pv) {
    __shared__ short lsA[8 * 128 * 8];
    __shared__ short lsB[8 * 128 * 8];
    int b = blockIdx.x, s = 0;
    while (b >= pv.cum[s + 1]) s++;
    int rem = b - pv.cum[s];
    const int C = pv.C[s], nct = C >> 7;
    const int j = rem / (7 * nct); rem %= 7 * nct;
    const int rt = rem / nct, ct = rem % nct;
    const int tid = threadIdx.x, lane = tid & 63, w = tid >> 6;
    const int wm = (w >> 1) * 64, wn = (w & 1) * 64;
    const unsigned short* __restrict__ Hb = pv.Hb[s];
    const unsigned short* __restrict__ Vb = pv.Vb[s];

    #pragma unroll
    for (int q = 0; q < 2; ++q) {
        const int kq = w + q * 4;
        const char* ga = (const char*)Hb + ((size_t)(j * 8 + kq) * 896 + rt * 128) * 16 + lane * 16;
        const char* gb = (const char*)Vb + ((size_t)(j * 8 + kq) * C + ct * 128) * 16 + lane * 16;
        gll16(ga,        (char*)lsA + kq * 2048);
        gll16(ga + 1024, (char*)lsA + kq * 2048 + 1024);
        gll16(gb,        (char*)lsB + kq * 2048);
        gll16(gb + 1024, (char*)lsB + kq * 2048 + 1024);
    }
    __syncthreads();

    f32x4 acc[4][4];
    #pragma unroll
    for (int u = 0; u < 4; ++u)
        #pragma unroll
        for (int v = 0; v < 4; ++v)
            acc[u][v] = (f32x4){0.f, 0.f, 0.f, 0.f};

    const int r16 = lane & 15;
    #pragma unroll
    for (int ks = 0; ks < 2; ++ks) {
        const int half = ks * 4 + (lane >> 4);
        s16x8 av[4], bv[4];
        #pragma unroll
        for (int u = 0; u < 4; ++u) {
            av[u] = *reinterpret_cast<const s16x8*>(&lsA[((half * 128) + wm + 16 * u + r16) * 8]);
            bv[u] = *reinterpret_cast<const s16x8*>(&lsB[((half * 128) + wn + 16 * u + r16) * 8]);
        }
        #pragma unroll
        for (int u = 0; u < 4; ++u)
            #pragma unroll
            for (int v = 0; v < 4; ++v)
                acc[u][v] = __builtin_amdgcn_mfma_f32_16x16x32_bf16(av[u], bv[v], acc[u][v], 0, 0, 0);
    }

    #pragma unroll
    for (int u = 0; u < 4; ++u) {
        const int mb = rt * 128 + wm + 16 * u + (lane >> 4) * 4;
        #pragma unroll
        for (int rg = 0; rg < 4; ++rg) {
            const int mm = mb + rg;
            const int ii = mm / 56, e = mm % 56;
            if (e < 49) {
                float* orow = pv.out[s] + (((size_t)(ii * 16 + j)) * 49 + e) * C + ct * 128 + (lane & 15);
                #pragma unroll
                for (int v = 0; v < 4; ++v)
                    orow[wn + 16 * v] = acc[u][v][rg];
            }
        }
    }
}

extern "C" void kernel_launch(void* const* d_in, const int* in_sizes, int n_in,
                              void* d_out, int out_size, void* d_ws, size_t ws_size,
                              hipStream_t stream) {
    const float* acts[4] = {(const float*)d_in[0], (const float*)d_in[1],
                            (const float*)d_in[2], (const float*)d_in[3]};
    const int Cs[4] = {256, 512, 1024, 2048};

    char* w0 = (char*)d_ws;
    size_t off = 0;
    unsigned short *Pk[4], *Pk2[4], *Vb[4], *Hb[4];
    for (int s = 0; s < 4; ++s) { Pk[s]  = (unsigned short*)(w0 + off); off += (size_t)3584 * Cs[s]; }
    for (int s = 0; s < 4; ++s) { Pk2[s] = (unsigned short*)(w0 + off); off += (size_t)3584 * Cs[s]; }
    for (int s = 0; s < 4; ++s) { Vb[s]  = (unsigned short*)(w0 + off); off += (size_t)2048 * Cs[s]; }
    for (int s = 0; s < 4; ++s) { Hb[s]  = (unsigned short*)(w0 + off); off += (size_t)1835008; }

    const bool full = ws_size >= off + (size_t)15 * SPART * 4;
    int np[4];
    if (full) { np[0] = 1; np[1] = 2; np[2] = 4; np[3] = 8; }
    else      { np[0] = 1; np[1] = 1; np[2] = 1; np[3] = 1; }
    float* Sp[4];
    for (int s = 0; s < 4; ++s) { Sp[s] = (float*)(w0 + off); off += (size_t)np[s] * SPART * 4; }

    float* out = (float*)d_out;
    const size_t o1 = 0;
    const size_t o2 = o1 + (size_t)256 * 49 * 256;
    const size_t o3 = o2 + (size_t)256 * 49 * 512;
    const size_t o4 = o3 + (size_t)256 * 49 * 1024;
    const size_t h1 = o4 + (size_t)256 * 49 * 2048;
    const size_t h2 = h1 + (size_t)256 * 2401;
    const size_t h3 = h2 + (size_t)256 * 2401;
    const size_t h4 = h3 + (size_t)256 * 2401;
    float* heat[4] = {out + h1, out + h2, out + h3, out + h4};
    float* outs[4] = {out + o1, out + o2, out + o3, out + o4};

    pool_kernel<<<16 * 256, 256, 0, stream>>>(acts[0], Pk[0], Pk2[0], Vb[0], 256, 56, 8, 1);
    pool_kernel<<<16 * 128, 256, 0, stream>>>(acts[1], Pk[1], Pk2[1], Vb[1], 512, 28, 4, 4);
    pool_kernel<<<16 * 64,  256, 0, stream>>>(acts[2], Pk[2], Pk2[2], Vb[2], 1024, 14, 2, 16);
    pool_kernel<<<16 * 32,  256, 0, stream>>>(acts[3], Pk[3], Pk2[3], Vb[3], 2048, 7, 1, 64);

    GramParams g;
    g.cum[0] = 0;
    for (int s = 0; s < 4; ++s) {
        g.Pk[s] = Pk[s];
        g.Pk2[s] = Pk2[s];
        g.S[s] = Sp[s];
        g.Kblk[s] = 2 * Cs[s] / np[s];
        g.cum[s + 1] = g.cum[s] + np[s] * 49;
    }
    gram_kernel<<<g.cum[4], 256, 0, stream>>>(g);

    SoftParams sp;
    for (int s = 0; s < 4; ++s) {
        sp.S[s] = Sp[s]; sp.heat[s] = heat[s]; sp.Hb[s] = Hb[s]; sp.np[s] = np[s];
    }
    softmax_kernel<<<3136, 256, 0, stream>>>(sp);

    PvParams pv;
    pv.cum[0] = 0;
    for (int s = 0; s < 4; ++s) {
        pv.Hb[s] = Hb[s]; pv.Vb[s] = Vb[s]; pv.out[s] = outs[s]; pv.C[s] = Cs[s];
        pv.cum[s + 1] = pv.cum[s] + 16 * 7 * (Cs[s] >> 7);
    }
    pv_kernel<<<pv.cum[4], 256, 0, stream>>>(pv);
}

// Round 5
// 135.598 us; speedup vs baseline: 4.9004x; 1.2145x over previous
//
#include <hip/hip_runtime.h>
#include <hip/hip_bf16.h>
#include <cstdint>
#include <cstddef>

// B=16 images, 4 scales, pooled 7x7=49 spatial, rows padded to 56 (MROWS=896).
//
// pool_all : act -> Pk[s] bf16 k-grouped [2C/8][896][8]  ([hi,lo] per channel)
//                   Vb[s] bf16 k-grouped [16 j][8 kq][C][8] (V^T, f padded to 64)
// gram     : S = P·P^T exact-split bf16 MFMA. A=[hi,lo]; B pass1 = Pk (hi*hi+lo*lo),
//            pass2 operand derived IN-REGISTER by 16-bit dword rotate ([lo,hi]):
//            sum == (hi+lo)*(hi+lo) exactly (up to fp32 acc). split-K partials.
// softmax  : sums partials, softmax over f, writes heat (fp32 out) + Hb bf16
//                   Hb[s] [16 j][8 kq][896][8]  (heat, f padded to 64)
// pv       : out[(i,e),c] = sum_f Hb*Vb  bf16 MFMA; block=(s,j,ct,rt-parity),
//            V staged once, row-tile loop inside.

typedef __attribute__((ext_vector_type(8))) short s16x8;
typedef __attribute__((ext_vector_type(4))) float f32x4;
typedef __attribute__((ext_vector_type(4))) uint32_t u32x4;

#define SPART 802816   // 896*896

__device__ __forceinline__ unsigned short f2bf(float x) {
    uint32_t u = __float_as_uint(x);
    uint32_t r = (u + 0x7fff + ((u >> 16) & 1)) >> 16;
    return (unsigned short)r;
}
__device__ __forceinline__ float bf2f(unsigned short b) {
    return __uint_as_float(((uint32_t)b) << 16);
}
__device__ __forceinline__ void gll16(const void* g, void* l) {
    __builtin_amdgcn_global_load_lds(
        (const __attribute__((address_space(1))) uint32_t*)g,
        (__attribute__((address_space(3))) uint32_t*)l, 16, 0, 0);
}

struct PoolParams {
    const float* act[4];
    unsigned short* Pk[4];
    unsigned short* Vb[4];
    int C[4], H[4], k[4], G[4], cum[5];
};

__global__ __launch_bounds__(256) void pool_all_kernel(PoolParams pp) {
    __shared__ alignas(16) float plane[3136];
    int b = blockIdx.x, s = 0;
    while (b >= pp.cum[s + 1]) s++;
    const int rem = b - pp.cum[s];
    const int C = pp.C[s], H = pp.H[s], k = pp.k[s], G = pp.G[s];
    const int HW = H * H;
    const int nblk_c = C / G;
    const int i  = rem / nblk_c;
    const int c0 = (rem % nblk_c) * G;
    unsigned short* __restrict__ Pk = pp.Pk[s];
    unsigned short* __restrict__ Vb = pp.Vb[s];

    const float4* src4 = reinterpret_cast<const float4*>(pp.act[s] + ((size_t)i * C + c0) * HW);
    float4* plane4 = reinterpret_cast<float4*>(plane);
    for (int idx = threadIdx.x; idx < (G * HW) >> 2; idx += 256)
        plane4[idx] = src4[idx];
    __syncthreads();
    for (int idx = threadIdx.x; idx < G * 49; idx += 256) {
        const int e = idx / G, g = idx % G;
        const int eh = e / 7, ew = e % 7;
        const float* ppl = plane + g * HW + (eh * k) * H + ew * k;
        float m = -INFINITY;
        for (int dy = 0; dy < k; ++dy)
            for (int dx = 0; dx < k; ++dx)
                m = fmaxf(m, ppl[dy * H + dx]);
        const int c = c0 + g;
        const unsigned short hb = f2bf(m);
        const unsigned short lb = f2bf(m - bf2f(hb));
        const size_t pk = (((size_t)(c >> 2) * 896) + (size_t)i * 56 + e) * 8 + ((c & 3) * 2);
        *reinterpret_cast<uint32_t*>(&Pk[pk]) = (uint32_t)hb | ((uint32_t)lb << 16);
        const size_t vb = (((size_t)i * 8 + (e >> 3)) * C + c) * 8 + (e & 7);
        Vb[vb] = hb;
    }
    // Pk pad rows e=49..55 -> zero
    for (int idx = threadIdx.x; idx < 7 * G; idx += 256) {
        const int e = 49 + idx / G, g = idx % G, c = c0 + g;
        const size_t pk = (((size_t)(c >> 2) * 896) + (size_t)i * 56 + e) * 8 + ((c & 3) * 2);
        *reinterpret_cast<uint32_t*>(&Pk[pk]) = 0;
    }
    // Vb pad f=49..63 -> zero
    for (int idx = threadIdx.x; idx < 15 * G; idx += 256) {
        const int e = 49 + idx / G, g = idx % G, c = c0 + g;
        const size_t vb = (((size_t)i * 8 + (e >> 3)) * C + c) * 8 + (e & 7);
        Vb[vb] = 0;
    }
}

struct GramParams {
    const unsigned short* Pk[4];
    float* S[4];
    int Kblk[4];   // k' elements per block per pass (=2C/np)
    int cum[5];
};

__global__ __launch_bounds__(256) void gram_kernel(GramParams g) {
    __shared__ short lsA[4 * 128 * 8];
    __shared__ short lsB[4 * 128 * 8];
    int b = blockIdx.x, s = 0;
    while (b >= g.cum[s + 1]) s++;
    const int rem = b - g.cum[s];
    const int p = rem / 49, t = rem % 49;
    const int bi = t / 7, bj = t % 7;
    const int Kb = g.Kblk[s];
    const int kg0 = p * (Kb >> 3);
    const unsigned short* __restrict__ Pk = g.Pk[s];
    float* __restrict__ S = g.S[s] + (size_t)p * SPART;

    const int tid = threadIdx.x, lane = tid & 63, w = tid >> 6;
    const int wm = (w >> 1) * 64, wn = (w & 1) * 64;

    f32x4 acc[4][4];
    #pragma unroll
    for (int u = 0; u < 4; ++u)
        #pragma unroll
        for (int v = 0; v < 4; ++v)
            acc[u][v] = (f32x4){0.f, 0.f, 0.f, 0.f};

    const int half = lane >> 4, r16 = lane & 15;
    for (int it = 0; it < (Kb >> 5); ++it) {
        const int kq = kg0 + it * 4 + w;
        const char* ga = (const char*)Pk + ((size_t)kq * 896 + bi * 128) * 16 + lane * 16;
        const char* gb = (const char*)Pk + ((size_t)kq * 896 + bj * 128) * 16 + lane * 16;
        gll16(ga,        (char*)lsA + w * 2048);
        gll16(ga + 1024, (char*)lsA + w * 2048 + 1024);
        gll16(gb,        (char*)lsB + w * 2048);
        gll16(gb + 1024, (char*)lsB + w * 2048 + 1024);
        __syncthreads();
        s16x8 av[4], bv[4], cv[4];
        #pragma unroll
        for (int u = 0; u < 4; ++u) {
            av[u] = *reinterpret_cast<const s16x8*>(&lsA[((half * 128) + wm + 16 * u + r16) * 8]);
            union { u32x4 u4; s16x8 s8; } ub, uc;
            ub.u4 = *reinterpret_cast<const u32x4*>(&lsB[((half * 128) + wn + 16 * u + r16) * 8]);
            uc.u4 = (ub.u4 >> 16) | (ub.u4 << 16);   // [hi,lo] -> [lo,hi] per dword
            bv[u] = ub.s8;
            cv[u] = uc.s8;
        }
        #pragma unroll
        for (int u = 0; u < 4; ++u)
            #pragma unroll
            for (int v = 0; v < 4; ++v) {
                acc[u][v] = __builtin_amdgcn_mfma_f32_16x16x32_bf16(av[u], bv[v], acc[u][v], 0, 0, 0);
                acc[u][v] = __builtin_amdgcn_mfma_f32_16x16x32_bf16(av[u], cv[v], acc[u][v], 0, 0, 0);
            }
        __syncthreads();
    }

    const int rowb = bi * 128 + wm + (lane >> 4) * 4;
    const int colb = bj * 128 + wn + (lane & 15);
    #pragma unroll
    for (int u = 0; u < 4; ++u)
        #pragma unroll
        for (int v = 0; v < 4; ++v)
            #pragma unroll
            for (int rg = 0; rg < 4; ++rg)
                S[(size_t)(rowb + 16 * u + rg) * 896 + colb + 16 * v] = acc[u][v][rg];
}

struct SoftParams {
    const float* S[4];
    float* heat[4];
    unsigned short* Hb[4];
    int np[4];
};

__global__ __launch_bounds__(256) void softmax_kernel(SoftParams sp) {
    const int grp = (blockIdx.x * 256 + threadIdx.x) >> 4;
    const int l = threadIdx.x & 15;
    const int s = grp / 12544;
    const int rem = grp % 12544;
    const int i = rem / 784;
    const int j = (rem / 49) % 16;
    const int e = rem % 49;
    const float* __restrict__ Sb = sp.S[s];
    const int np = sp.np[s];
    const size_t rowoff = ((size_t)(i * 56 + e)) * 896 + j * 56;

    float v[4];
    #pragma unroll
    for (int t = 0; t < 4; ++t) {
        const int f = l + t * 16;
        float x = -INFINITY;
        if (f < 49) {
            x = 0.f;
            for (int p = 0; p < np; ++p) x += Sb[(size_t)p * SPART + rowoff + f];
        }
        v[t] = x;
    }
    float m = fmaxf(fmaxf(v[0], v[1]), fmaxf(v[2], v[3]));
    #pragma unroll
    for (int d = 1; d < 16; d <<= 1) m = fmaxf(m, __shfl_xor(m, d, 16));
    float ex[4], sum = 0.f;
    #pragma unroll
    for (int t = 0; t < 4; ++t) {
        const int f = l + t * 16;
        ex[t] = (f < 49) ? __expf(v[t] - m) : 0.f;
        sum += ex[t];
    }
    #pragma unroll
    for (int d = 1; d < 16; d <<= 1) sum += __shfl_xor(sum, d, 16);
    const float inv = 1.f / sum;

    float* hrow = sp.heat[s] + (((size_t)(i * 16 + j)) * 49 + e) * 49;
    unsigned short* __restrict__ Hb = sp.Hb[s];
    const size_t hbrow = (size_t)i * 56 + e;
    #pragma unroll
    for (int t = 0; t < 4; ++t) {
        const int f = l + t * 16;
        const float hv = (f < 49) ? ex[t] * inv : 0.f;
        if (f < 49) hrow[f] = hv;
        Hb[(((size_t)j * 8 + (f >> 3)) * 896 + hbrow) * 8 + (f & 7)] = f2bf(hv);
    }
}

struct PvParams {
    const unsigned short* Hb[4];
    const unsigned short* Vb[4];
    float* out[4];
    int C[4];
    int cum[5];
};

__global__ __launch_bounds__(256) void pv_kernel(PvParams pv) {
    __shared__ short lsA[8 * 128 * 8];   // Hb tile (per rt)
    __shared__ short lsB[8 * 128 * 8];   // Vb tile (staged once)
    int b = blockIdx.x, s = 0;
    while (b >= pv.cum[s + 1]) s++;
    int rem = b - pv.cum[s];
    const int C = pv.C[s], nct = C >> 7;
    const int j  = rem / (nct * 2); rem %= nct * 2;
    const int ct = rem >> 1, rh = rem & 1;
    const int tid = threadIdx.x, lane = tid & 63, w = tid >> 6;
    const int wm = (w >> 1) * 64, wn = (w & 1) * 64;
    const unsigned short* __restrict__ Hb = pv.Hb[s];
    const unsigned short* __restrict__ Vb = pv.Vb[s];

    // stage V tile once: 8 kq x 128 c
    #pragma unroll
    for (int q = 0; q < 2; ++q) {
        const int kq = w + q * 4;
        const char* gb = (const char*)Vb + ((size_t)(j * 8 + kq) * C + ct * 128) * 16 + lane * 16;
        gll16(gb,        (char*)lsB + kq * 2048);
        gll16(gb + 1024, (char*)lsB + kq * 2048 + 1024);
    }

    const int r16 = lane & 15;
    for (int rt = rh; rt < 7; rt += 2) {
        #pragma unroll
        for (int q = 0; q < 2; ++q) {
            const int kq = w + q * 4;
            const char* ga = (const char*)Hb + ((size_t)(j * 8 + kq) * 896 + rt * 128) * 16 + lane * 16;
            gll16(ga,        (char*)lsA + kq * 2048);
            gll16(ga + 1024, (char*)lsA + kq * 2048 + 1024);
        }
        __syncthreads();

        f32x4 acc[4][4];
        #pragma unroll
        for (int u = 0; u < 4; ++u)
            #pragma unroll
            for (int v = 0; v < 4; ++v)
                acc[u][v] = (f32x4){0.f, 0.f, 0.f, 0.f};

        #pragma unroll
        for (int ks = 0; ks < 2; ++ks) {
            const int half = ks * 4 + (lane >> 4);
            s16x8 av[4], bv[4];
            #pragma unroll
            for (int u = 0; u < 4; ++u) {
                av[u] = *reinterpret_cast<const s16x8*>(&lsA[((half * 128) + wm + 16 * u + r16) * 8]);
                bv[u] = *reinterpret_cast<const s16x8*>(&lsB[((half * 128) + wn + 16 * u + r16) * 8]);
            }
            #pragma unroll
            for (int u = 0; u < 4; ++u)
                #pragma unroll
                for (int v = 0; v < 4; ++v)
                    acc[u][v] = __builtin_amdgcn_mfma_f32_16x16x32_bf16(av[u], bv[v], acc[u][v], 0, 0, 0);
        }

        #pragma unroll
        for (int u = 0; u < 4; ++u) {
            const int mb = rt * 128 + wm + 16 * u + (lane >> 4) * 4;
            #pragma unroll
            for (int rg = 0; rg < 4; ++rg) {
                const int mm = mb + rg;
                const int ii = mm / 56, e = mm % 56;
                if (e < 49) {
                    float* orow = pv.out[s] + (((size_t)(ii * 16 + j)) * 49 + e) * C + ct * 128 + (lane & 15);
                    #pragma unroll
                    for (int v = 0; v < 4; ++v)
                        orow[wn + 16 * v] = acc[u][v][rg];
                }
            }
        }
        __syncthreads();   // protect lsA before next rt staging
    }
}

extern "C" void kernel_launch(void* const* d_in, const int* in_sizes, int n_in,
                              void* d_out, int out_size, void* d_ws, size_t ws_size,
                              hipStream_t stream) {
    const int Cs[4] = {256, 512, 1024, 2048};
    const int Hs[4] = {56, 28, 14, 7};
    const int ks[4] = {8, 4, 2, 1};
    const int Gs[4] = {1, 4, 16, 64};

    char* w0 = (char*)d_ws;
    size_t off = 0;
    unsigned short *Pk[4], *Vb[4], *Hb[4];
    for (int s = 0; s < 4; ++s) { Pk[s] = (unsigned short*)(w0 + off); off += (size_t)3584 * Cs[s]; }
    for (int s = 0; s < 4; ++s) { Vb[s] = (unsigned short*)(w0 + off); off += (size_t)2048 * Cs[s]; }
    for (int s = 0; s < 4; ++s) { Hb[s] = (unsigned short*)(w0 + off); off += (size_t)1835008; }

    int np[4] = {1, 2, 2, 4};
    {
        size_t need = off;
        for (int s = 0; s < 4; ++s) need += (size_t)np[s] * SPART * 4;
        if (ws_size < need) { np[0] = np[1] = np[2] = np[3] = 1; }
    }
    float* Sp[4];
    for (int s = 0; s < 4; ++s) { Sp[s] = (float*)(w0 + off); off += (size_t)np[s] * SPART * 4; }

    float* out = (float*)d_out;
    const size_t o1 = 0;
    const size_t o2 = o1 + (size_t)256 * 49 * 256;
    const size_t o3 = o2 + (size_t)256 * 49 * 512;
    const size_t o4 = o3 + (size_t)256 * 49 * 1024;
    const size_t h1 = o4 + (size_t)256 * 49 * 2048;
    const size_t h2 = h1 + (size_t)256 * 2401;
    const size_t h3 = h2 + (size_t)256 * 2401;
    const size_t h4 = h3 + (size_t)256 * 2401;
    float* heat[4] = {out + h1, out + h2, out + h3, out + h4};
    float* outs[4] = {out + o1, out + o2, out + o3, out + o4};

    PoolParams pp;
    pp.cum[0] = 0;
    for (int s = 0; s < 4; ++s) {
        pp.act[s] = (const float*)d_in[s];
        pp.Pk[s] = Pk[s]; pp.Vb[s] = Vb[s];
        pp.C[s] = Cs[s]; pp.H[s] = Hs[s]; pp.k[s] = ks[s]; pp.G[s] = Gs[s];
        pp.cum[s + 1] = pp.cum[s] + 16 * (Cs[s] / Gs[s]);
    }
    pool_all_kernel<<<pp.cum[4], 256, 0, stream>>>(pp);

    GramParams g;
    g.cum[0] = 0;
    for (int s = 0; s < 4; ++s) {
        g.Pk[s] = Pk[s];
        g.S[s] = Sp[s];
        g.Kblk[s] = 2 * Cs[s] / np[s];
        g.cum[s + 1] = g.cum[s] + np[s] * 49;
    }
    gram_kernel<<<g.cum[4], 256, 0, stream>>>(g);

    SoftParams sp;
    for (int s = 0; s < 4; ++s) {
        sp.S[s] = Sp[s]; sp.heat[s] = heat[s]; sp.Hb[s] = Hb[s]; sp.np[s] = np[s];
    }
    softmax_kernel<<<3136, 256, 0, stream>>>(sp);

    PvParams pv;
    pv.cum[0] = 0;
    for (int s = 0; s < 4; ++s) {
        pv.Hb[s] = Hb[s]; pv.Vb[s] = Vb[s]; pv.out[s] = outs[s]; pv.C[s] = Cs[s];
        pv.cum[s + 1] = pv.cum[s] + 16 * (Cs[s] >> 7) * 2;
    }
    pv_kernel<<<pv.cum[4], 256, 0, stream>>>(pv);
}

// Round 6
// 132.122 us; speedup vs baseline: 5.0294x; 1.0263x over previous
//
#include <hip/hip_runtime.h>
#include <hip/hip_bf16.h>
#include <cstdint>
#include <cstddef>

// B=16 images, 4 scales, pooled 7x7=49 spatial, rows padded to 56 (MROWS=896).
//
// pool_all : act -> Pk[s] bf16 k-grouped [2C/8][896][8]  ([hi,lo] per channel)
//                   Vb[s] bf16 k-grouped [16 j][8 kq][C][8] (V^T, f padded to 64)
// gram     : S = P·P^T exact-split bf16 MFMA. A=[hi,lo]; B pass1 = Pk (hi*hi+lo*lo),
//            pass2 operand derived IN-REGISTER by 16-bit dword rotate ([lo,hi]):
//            sum == (hi+lo)*(hi+lo) exactly (up to fp32 acc). split-K partials.
//            Double-buffered LDS: stage(t+1) issued before MFMA(t), single
//            vmcnt(0)+s_barrier per K-step (loads in flight under compute).
// softmax  : sums partials, softmax over f, writes heat (fp32 out) + Hb bf16
//                   Hb[s] [16 j][8 kq][896][8]  (heat, f padded to 64)
// pv       : out[(i,e),c] = sum_f Hb*Vb  bf16 MFMA; flat block=(s,j,rt,ct):
//            one stage + one barrier, stores drain async (no mid-loop vmcnt
//            that would serialize on store retirement).

typedef __attribute__((ext_vector_type(8))) short s16x8;
typedef __attribute__((ext_vector_type(4))) float f32x4;
typedef __attribute__((ext_vector_type(4))) uint32_t u32x4;

#define SPART 802816   // 896*896

__device__ __forceinline__ unsigned short f2bf(float x) {
    uint32_t u = __float_as_uint(x);
    uint32_t r = (u + 0x7fff + ((u >> 16) & 1)) >> 16;
    return (unsigned short)r;
}
__device__ __forceinline__ float bf2f(unsigned short b) {
    return __uint_as_float(((uint32_t)b) << 16);
}
__device__ __forceinline__ void gll16(const void* g, void* l) {
    __builtin_amdgcn_global_load_lds(
        (const __attribute__((address_space(1))) uint32_t*)g,
        (__attribute__((address_space(3))) uint32_t*)l, 16, 0, 0);
}

struct PoolParams {
    const float* act[4];
    unsigned short* Pk[4];
    unsigned short* Vb[4];
    int C[4], H[4], k[4], G[4], cum[5];
};

__global__ __launch_bounds__(256) void pool_all_kernel(PoolParams pp) {
    __shared__ alignas(16) float plane[3136];
    int b = blockIdx.x, s = 0;
    while (b >= pp.cum[s + 1]) s++;
    const int rem = b - pp.cum[s];
    const int C = pp.C[s], H = pp.H[s], k = pp.k[s], G = pp.G[s];
    const int HW = H * H;
    const int nblk_c = C / G;
    const int i  = rem / nblk_c;
    const int c0 = (rem % nblk_c) * G;
    unsigned short* __restrict__ Pk = pp.Pk[s];
    unsigned short* __restrict__ Vb = pp.Vb[s];

    const float4* src4 = reinterpret_cast<const float4*>(pp.act[s] + ((size_t)i * C + c0) * HW);
    float4* plane4 = reinterpret_cast<float4*>(plane);
    for (int idx = threadIdx.x; idx < (G * HW) >> 2; idx += 256)
        plane4[idx] = src4[idx];
    __syncthreads();
    for (int idx = threadIdx.x; idx < G * 49; idx += 256) {
        const int e = idx / G, g = idx % G;
        const int eh = e / 7, ew = e % 7;
        const float* ppl = plane + g * HW + (eh * k) * H + ew * k;
        float m = -INFINITY;
        for (int dy = 0; dy < k; ++dy)
            for (int dx = 0; dx < k; ++dx)
                m = fmaxf(m, ppl[dy * H + dx]);
        const int c = c0 + g;
        const unsigned short hb = f2bf(m);
        const unsigned short lb = f2bf(m - bf2f(hb));
        const size_t pk = (((size_t)(c >> 2) * 896) + (size_t)i * 56 + e) * 8 + ((c & 3) * 2);
        *reinterpret_cast<uint32_t*>(&Pk[pk]) = (uint32_t)hb | ((uint32_t)lb << 16);
        const size_t vb = (((size_t)i * 8 + (e >> 3)) * C + c) * 8 + (e & 7);
        Vb[vb] = hb;
    }
    for (int idx = threadIdx.x; idx < 7 * G; idx += 256) {
        const int e = 49 + idx / G, g = idx % G, c = c0 + g;
        const size_t pk = (((size_t)(c >> 2) * 896) + (size_t)i * 56 + e) * 8 + ((c & 3) * 2);
        *reinterpret_cast<uint32_t*>(&Pk[pk]) = 0;
    }
    for (int idx = threadIdx.x; idx < 15 * G; idx += 256) {
        const int e = 49 + idx / G, g = idx % G, c = c0 + g;
        const size_t vb = (((size_t)i * 8 + (e >> 3)) * C + c) * 8 + (e & 7);
        Vb[vb] = 0;
    }
}

struct GramParams {
    const unsigned short* Pk[4];
    float* S[4];
    int Kblk[4];   // k' elements per block per pass (=2C/np)
    int cum[5];
};

__global__ __launch_bounds__(256) void gram_kernel(GramParams g) {
    __shared__ short lsA[2][4096];   // 2 x 8KB
    __shared__ short lsB[2][4096];
    int b = blockIdx.x, s = 0;
    while (b >= g.cum[s + 1]) s++;
    const int rem = b - g.cum[s];
    const int p = rem / 49, t = rem % 49;
    const int bi = t / 7, bj = t % 7;
    const int Kb = g.Kblk[s];
    const int kg0 = p * (Kb >> 3);
    const unsigned short* __restrict__ Pk = g.Pk[s];
    float* __restrict__ S = g.S[s] + (size_t)p * SPART;

    const int tid = threadIdx.x, lane = tid & 63, w = tid >> 6;
    const int wm = (w >> 1) * 64, wn = (w & 1) * 64;

    f32x4 acc[4][4];
    #pragma unroll
    for (int u = 0; u < 4; ++u)
        #pragma unroll
        for (int v = 0; v < 4; ++v)
            acc[u][v] = (f32x4){0.f, 0.f, 0.f, 0.f};

    const int half = lane >> 4, r16 = lane & 15;
    const int nt = Kb >> 5;

#define GSTAGE(buf, it) do {                                                        \
        const int kq_ = kg0 + (it) * 4 + w;                                         \
        const char* ga_ = (const char*)Pk + ((size_t)kq_ * 896 + bi * 128) * 16 + lane * 16; \
        const char* gb_ = (const char*)Pk + ((size_t)kq_ * 896 + bj * 128) * 16 + lane * 16; \
        gll16(ga_,        (char*)lsA[buf] + w * 2048);                              \
        gll16(ga_ + 1024, (char*)lsA[buf] + w * 2048 + 1024);                       \
        gll16(gb_,        (char*)lsB[buf] + w * 2048);                              \
        gll16(gb_ + 1024, (char*)lsB[buf] + w * 2048 + 1024);                       \
    } while (0)

    GSTAGE(0, 0);
    asm volatile("s_waitcnt vmcnt(0)" ::: "memory");
    __builtin_amdgcn_s_barrier();

    int cur = 0;
    for (int it = 0; it < nt; ++it) {
        if (it + 1 < nt) GSTAGE(cur ^ 1, it + 1);   // prefetch under compute
        s16x8 av[4], bv[4], cv[4];
        #pragma unroll
        for (int u = 0; u < 4; ++u) {
            av[u] = *reinterpret_cast<const s16x8*>(&lsA[cur][((half * 128) + wm + 16 * u + r16) * 8]);
            union { u32x4 u4; s16x8 s8; } ub, uc;
            ub.u4 = *reinterpret_cast<const u32x4*>(&lsB[cur][((half * 128) + wn + 16 * u + r16) * 8]);
            uc.u4 = (ub.u4 >> 16) | (ub.u4 << 16);   // [hi,lo] -> [lo,hi] per dword
            bv[u] = ub.s8;
            cv[u] = uc.s8;
        }
        #pragma unroll
        for (int u = 0; u < 4; ++u)
            #pragma unroll
            for (int v = 0; v < 4; ++v) {
                acc[u][v] = __builtin_amdgcn_mfma_f32_16x16x32_bf16(av[u], bv[v], acc[u][v], 0, 0, 0);
                acc[u][v] = __builtin_amdgcn_mfma_f32_16x16x32_bf16(av[u], cv[v], acc[u][v], 0, 0, 0);
            }
        __builtin_amdgcn_sched_barrier(0);
        asm volatile("s_waitcnt vmcnt(0)" ::: "memory");   // next tile landed
        __builtin_amdgcn_s_barrier();
        cur ^= 1;
    }
#undef GSTAGE

    const int rowb = bi * 128 + wm + (lane >> 4) * 4;
    const int colb = bj * 128 + wn + (lane & 15);
    #pragma unroll
    for (int u = 0; u < 4; ++u)
        #pragma unroll
        for (int v = 0; v < 4; ++v)
            #pragma unroll
            for (int rg = 0; rg < 4; ++rg)
                S[(size_t)(rowb + 16 * u + rg) * 896 + colb + 16 * v] = acc[u][v][rg];
}

struct SoftParams {
    const float* S[4];
    float* heat[4];
    unsigned short* Hb[4];
    int np[4];
};

__global__ __launch_bounds__(256) void softmax_kernel(SoftParams sp) {
    const int grp = (blockIdx.x * 256 + threadIdx.x) >> 4;
    const int l = threadIdx.x & 15;
    const int s = grp / 12544;
    const int rem = grp % 12544;
    const int i = rem / 784;
    const int j = (rem / 49) % 16;
    const int e = rem % 49;
    const float* __restrict__ Sb = sp.S[s];
    const int np = sp.np[s];
    const size_t rowoff = ((size_t)(i * 56 + e)) * 896 + j * 56;

    float v[4];
    #pragma unroll
    for (int t = 0; t < 4; ++t) {
        const int f = l + t * 16;
        float x = -INFINITY;
        if (f < 49) {
            x = 0.f;
            for (int p = 0; p < np; ++p) x += Sb[(size_t)p * SPART + rowoff + f];
        }
        v[t] = x;
    }
    float m = fmaxf(fmaxf(v[0], v[1]), fmaxf(v[2], v[3]));
    #pragma unroll
    for (int d = 1; d < 16; d <<= 1) m = fmaxf(m, __shfl_xor(m, d, 16));
    float ex[4], sum = 0.f;
    #pragma unroll
    for (int t = 0; t < 4; ++t) {
        const int f = l + t * 16;
        ex[t] = (f < 49) ? __expf(v[t] - m) : 0.f;
        sum += ex[t];
    }
    #pragma unroll
    for (int d = 1; d < 16; d <<= 1) sum += __shfl_xor(sum, d, 16);
    const float inv = 1.f / sum;

    float* hrow = sp.heat[s] + (((size_t)(i * 16 + j)) * 49 + e) * 49;
    unsigned short* __restrict__ Hb = sp.Hb[s];
    const size_t hbrow = (size_t)i * 56 + e;
    #pragma unroll
    for (int t = 0; t < 4; ++t) {
        const int f = l + t * 16;
        const float hv = (f < 49) ? ex[t] * inv : 0.f;
        if (f < 49) hrow[f] = hv;
        Hb[(((size_t)j * 8 + (f >> 3)) * 896 + hbrow) * 8 + (f & 7)] = f2bf(hv);
    }
}

struct PvParams {
    const unsigned short* Hb[4];
    const unsigned short* Vb[4];
    float* out[4];
    int C[4];
    int cum[5];
};

__global__ __launch_bounds__(256) void pv_kernel(PvParams pv) {
    __shared__ short lsA[8 * 128 * 8];   // Hb tile 16KB
    __shared__ short lsB[8 * 128 * 8];   // Vb tile 16KB
    int b = blockIdx.x, s = 0;
    while (b >= pv.cum[s + 1]) s++;
    int rem = b - pv.cum[s];
    const int C = pv.C[s], nct = C >> 7;
    const int j = rem / (7 * nct); rem %= 7 * nct;
    const int rt = rem / nct, ct = rem % nct;   // consecutive blocks share (j,rt) Hb tile -> L2 hits
    const int tid = threadIdx.x, lane = tid & 63, w = tid >> 6;
    const int wm = (w >> 1) * 64, wn = (w & 1) * 64;
    const unsigned short* __restrict__ Hb = pv.Hb[s];
    const unsigned short* __restrict__ Vb = pv.Vb[s];

    #pragma unroll
    for (int q = 0; q < 2; ++q) {
        const int kq = w + q * 4;
        const char* ga = (const char*)Hb + ((size_t)(j * 8 + kq) * 896 + rt * 128) * 16 + lane * 16;
        const char* gb = (const char*)Vb + ((size_t)(j * 8 + kq) * C + ct * 128) * 16 + lane * 16;
        gll16(ga,        (char*)lsA + kq * 2048);
        gll16(ga + 1024, (char*)lsA + kq * 2048 + 1024);
        gll16(gb,        (char*)lsB + kq * 2048);
        gll16(gb + 1024, (char*)lsB + kq * 2048 + 1024);
    }
    __syncthreads();   // single drain per block; no prior stores pending

    f32x4 acc[4][4];
    #pragma unroll
    for (int u = 0; u < 4; ++u)
        #pragma unroll
        for (int v = 0; v < 4; ++v)
            acc[u][v] = (f32x4){0.f, 0.f, 0.f, 0.f};

    const int r16 = lane & 15;
    #pragma unroll
    for (int ks = 0; ks < 2; ++ks) {
        const int half = ks * 4 + (lane >> 4);
        s16x8 av[4], bv[4];
        #pragma unroll
        for (int u = 0; u < 4; ++u) {
            av[u] = *reinterpret_cast<const s16x8*>(&lsA[((half * 128) + wm + 16 * u + r16) * 8]);
            bv[u] = *reinterpret_cast<const s16x8*>(&lsB[((half * 128) + wn + 16 * u + r16) * 8]);
        }
        #pragma unroll
        for (int u = 0; u < 4; ++u)
            #pragma unroll
            for (int v = 0; v < 4; ++v)
                acc[u][v] = __builtin_amdgcn_mfma_f32_16x16x32_bf16(av[u], bv[v], acc[u][v], 0, 0, 0);
    }

    #pragma unroll
    for (int u = 0; u < 4; ++u) {
        const int mb = rt * 128 + wm + 16 * u + (lane >> 4) * 4;
        #pragma unroll
        for (int rg = 0; rg < 4; ++rg) {
            const int mm = mb + rg;
            const int ii = mm / 56, e = mm % 56;
            if (e < 49) {
                float* orow = pv.out[s] + (((size_t)(ii * 16 + j)) * 49 + e) * C + ct * 128 + (lane & 15);
                #pragma unroll
                for (int v = 0; v < 4; ++v)
                    orow[wn + 16 * v] = acc[u][v][rg];
            }
        }
    }
    // stores drain asynchronously; kernel-end waits once
}

extern "C" void kernel_launch(void* const* d_in, const int* in_sizes, int n_in,
                              void* d_out, int out_size, void* d_ws, size_t ws_size,
                              hipStream_t stream) {
    const int Cs[4] = {256, 512, 1024, 2048};
    const int Hs[4] = {56, 28, 14, 7};
    const int ks[4] = {8, 4, 2, 1};
    const int Gs[4] = {1, 4, 16, 64};

    char* w0 = (char*)d_ws;
    size_t off = 0;
    unsigned short *Pk[4], *Vb[4], *Hb[4];
    for (int s = 0; s < 4; ++s) { Pk[s] = (unsigned short*)(w0 + off); off += (size_t)3584 * Cs[s]; }
    for (int s = 0; s < 4; ++s) { Vb[s] = (unsigned short*)(w0 + off); off += (size_t)2048 * Cs[s]; }
    for (int s = 0; s < 4; ++s) { Hb[s] = (unsigned short*)(w0 + off); off += (size_t)1835008; }

    int np[4] = {1, 2, 2, 4};
    {
        size_t need = off;
        for (int s = 0; s < 4; ++s) need += (size_t)np[s] * SPART * 4;
        if (ws_size < need) { np[0] = np[1] = np[2] = np[3] = 1; }
    }
    float* Sp[4];
    for (int s = 0; s < 4; ++s) { Sp[s] = (float*)(w0 + off); off += (size_t)np[s] * SPART * 4; }

    float* out = (float*)d_out;
    const size_t o1 = 0;
    const size_t o2 = o1 + (size_t)256 * 49 * 256;
    const size_t o3 = o2 + (size_t)256 * 49 * 512;
    const size_t o4 = o3 + (size_t)256 * 49 * 1024;
    const size_t h1 = o4 + (size_t)256 * 49 * 2048;
    const size_t h2 = h1 + (size_t)256 * 2401;
    const size_t h3 = h2 + (size_t)256 * 2401;
    const size_t h4 = h3 + (size_t)256 * 2401;
    float* heat[4] = {out + h1, out + h2, out + h3, out + h4};
    float* outs[4] = {out + o1, out + o2, out + o3, out + o4};

    PoolParams pp;
    pp.cum[0] = 0;
    for (int s = 0; s < 4; ++s) {
        pp.act[s] = (const float*)d_in[s];
        pp.Pk[s] = Pk[s]; pp.Vb[s] = Vb[s];
        pp.C[s] = Cs[s]; pp.H[s] = Hs[s]; pp.k[s] = ks[s]; pp.G[s] = Gs[s];
        pp.cum[s + 1] = pp.cum[s] + 16 * (Cs[s] / Gs[s]);
    }
    pool_all_kernel<<<pp.cum[4], 256, 0, stream>>>(pp);

    GramParams g;
    g.cum[0] = 0;
    for (int s = 0; s < 4; ++s) {
        g.Pk[s] = Pk[s];
        g.S[s] = Sp[s];
        g.Kblk[s] = 2 * Cs[s] / np[s];
        g.cum[s + 1] = g.cum[s] + np[s] * 49;
    }
    gram_kernel<<<g.cum[4], 256, 0, stream>>>(g);

    SoftParams sp;
    for (int s = 0; s < 4; ++s) {
        sp.S[s] = Sp[s]; sp.heat[s] = heat[s]; sp.Hb[s] = Hb[s]; sp.np[s] = np[s];
    }
    softmax_kernel<<<3136, 256, 0, stream>>>(sp);

    PvParams pv;
    pv.cum[0] = 0;
    for (int s = 0; s < 4; ++s) {
        pv.Hb[s] = Hb[s]; pv.Vb[s] = Vb[s]; pv.out[s] = outs[s]; pv.C[s] = Cs[s];
        pv.cum[s + 1] = pv.cum[s] + 16 * 7 * (Cs[s] >> 7);
    }
    pv_kernel<<<pv.cum[4], 256, 0, stream>>>(pv);
}